// Round 3
// baseline (466.660 us; speedup 1.0000x reference)
//
#include <hip/hip_runtime.h>

#define B_   32
#define S_   1024
#define V_   32000
#define E_   256
#define H_   512
#define D2_  1124
#define IN_  1380
#define INP_ 1408
#define G3_  1536
#define VO_  32012   // V + MAX_OOVS
#define NKT_ 36      // K tiles of 32 covering 1152 (1124 padded)

typedef __bf16 bf16x8 __attribute__((ext_vector_type(8)));
typedef float  f32x4  __attribute__((ext_vector_type(4)));

static __device__ __forceinline__ unsigned short f2bf(float f) {
    union { float f; unsigned int u; } v; v.f = f;
    unsigned int u = v.u;
    unsigned int r = (u + 0x7FFFu + ((u >> 16) & 1u)) >> 16;  // RNE
    return (unsigned short)r;
}

// pack two f32 (as u32 bits) into two bf16 (round half up)
static __device__ __forceinline__ unsigned int pkbf(unsigned int a, unsigned int b) {
    return ((a + 0x8000u) >> 16) | ((b + 0x8000u) & 0xffff0000u);
}

static __device__ __forceinline__ uint4 pack4(uint4 a, uint4 b) {
    uint4 o;
    o.x = pkbf(a.x, a.y); o.y = pkbf(a.z, a.w);
    o.z = pkbf(b.x, b.y); o.w = pkbf(b.z, b.w);
    return o;
}

static __device__ __forceinline__ uint4 pack_bin(unsigned int binu, int kbase) {
    unsigned int x[8];
#pragma unroll
    for (int j = 0; j < 8; j++) x[j] = (kbase + j < D2_) ? binu : 0u;
    uint4 o;
    o.x = pkbf(x[0], x[1]); o.y = pkbf(x[2], x[3]);
    o.z = pkbf(x[4], x[5]); o.w = pkbf(x[6], x[7]);
    return o;
}

// tanh via hw exp2/rcp: tanh(x) = 1 - 2/(e^{2x}+1); rel err ~1e-7
static __device__ __forceinline__ float tanh_fast(float x) {
    float e = __builtin_amdgcn_exp2f(x * 2.8853901817f);   // e^{2x}
    return 1.0f - 2.0f * __builtin_amdgcn_rcpf(e + 1.0f);
}

// ---------------- order handling: effective prev_state / weighted ----------------
__global__ void k_prep0(const int* order, const float* prev, const float* weighted,
                        const float* encoded, const float* bin,
                        const float* Ws_w, const float* Ws_b,
                        float* prev_eff, float* weff) {
    int b = blockIdx.x, t = threadIdx.x;
    if (order[0] != 0) {
        for (int i = t; i < H_;  i += 256) prev_eff[b * H_ + i] = prev[b * H_ + i];
        for (int i = t; i < D2_; i += 256) weff[b * D2_ + i] = weighted[b * D2_ + i];
    } else {
        for (int i = t; i < D2_; i += 256) weff[b * D2_ + i] = 0.0f;
        const float* encrow = encoded + ((size_t)(b * S_ + (S_ - 1))) * 1024;
        float bv = bin[b * S_ + (S_ - 1)];
        for (int h = t; h < H_; h += 256) {
            float acc = Ws_b[h];
            const float* wr = Ws_w + (size_t)h * D2_;
            for (int d = 0; d < 1024; d++) acc += encrow[d] * wr[d];
            for (int d = 1024; d < D2_; d++) acc += bv * wr[d];
            prev_eff[b * H_ + h] = acc;
        }
    }
}

// ---------------- build x = [emb, weighted], padded to 1408 with zeros ----------------
__global__ void k_build_x(const int* input_idx, const float* embed, const float* weff, float* x) {
    int idx = blockIdx.x * 256 + threadIdx.x;   // 32*1408 exact
    int b = idx / INP_, d = idx % INP_;
    float v;
    if (d < E_)        v = embed[(size_t)input_idx[b] * E_ + d];
    else if (d < IN_)  v = weff[b * D2_ + (d - E_)];
    else               v = 0.0f;
    x[idx] = v;
}

// ---------------- pack Wc_w into MFMA B-fragment layout (bf16) ----------------
// bpack[((kt*32 + ht)*64 + lane)*8 + j] = Wc_w[ht*16 + (lane&15)][kt*32 + (lane>>4)*8 + j]
__global__ void k_pack_wc(const float* Wc_w, unsigned short* bpack) {
    int idx = blockIdx.x * 256 + threadIdx.x;   // 589824 exact
    int j = idx & 7, lane = (idx >> 3) & 63, ht = (idx >> 9) & 31, kt = idx >> 14;
    int h = ht * 16 + (lane & 15);
    int k = kt * 32 + (lane >> 4) * 8 + j;
    float v = (k < D2_) ? Wc_w[(size_t)h * D2_ + k] : 0.0f;
    bpack[idx] = f2bf(v);
}

// ---------------- gi = x @ W_ih.T + b_ih ----------------
__global__ void k_gi(const float* x, const float* W_ih, const float* b_ih, float* gi) {
    extern __shared__ float smemF[];            // 16 * 1408 floats
    int t = threadIdx.x;
    int bh = blockIdx.x & 1;
    int hq = blockIdx.x >> 1;
    const float4* xg = (const float4*)(x + (size_t)bh * 16 * INP_);
    float4* xl4 = (float4*)smemF;
    for (int j = t; j < 16 * INP_ / 4; j += 256) xl4[j] = xg[j];
    __syncthreads();
    int w = t >> 6, l = t & 63;
    int h3 = hq * 4 + w;
    const float* wr = W_ih + (size_t)h3 * IN_;
    float4 wv[6];
#pragma unroll
    for (int i = 0; i < 6; i++) {
        int k = 4 * l + 256 * i;
        if (k + 3 < IN_) wv[i] = *(const float4*)(wr + k);
        else {
            float a0 = (k     < IN_) ? wr[k]     : 0.f;
            float a1 = (k + 1 < IN_) ? wr[k + 1] : 0.f;
            float a2 = (k + 2 < IN_) ? wr[k + 2] : 0.f;
            float a3 = (k + 3 < IN_) ? wr[k + 3] : 0.f;
            wv[i] = make_float4(a0, a1, a2, a3);
        }
    }
    float bias = b_ih[h3];
    for (int bb = 0; bb < 16; bb++) {
        const float4* xr = xl4 + bb * (INP_ / 4);
        float p = 0.f;
#pragma unroll
        for (int i = 0; i < 6; i++) {
            int k = 4 * l + 256 * i;
            if (k < INP_) {
                float4 xv = xr[l + 64 * i];
                p += wv[i].x * xv.x + wv[i].y * xv.y + wv[i].z * xv.z + wv[i].w * xv.w;
            }
        }
#pragma unroll
        for (int off = 32; off >= 1; off >>= 1) p += __shfl_xor(p, off, 64);
        if (l == 0) gi[(bh * 16 + bb) * G3_ + h3] = p + bias;
    }
}

// ---------------- gh = prev_eff @ W_hh.T + b_hh ----------------
__global__ void k_gh(const float* prev_eff, const float* W_hh, const float* b_hh, float* gh) {
    extern __shared__ float smemF[];            // 32*512 floats
    int t = threadIdx.x;
    const float4* pg = (const float4*)prev_eff;
    float4* pl4 = (float4*)smemF;
    for (int j = t; j < B_ * H_ / 4; j += 256) pl4[j] = pg[j];
    __syncthreads();
    int w = t >> 6, l = t & 63;
    int h3 = blockIdx.x * 4 + w;
    const float* wr = W_hh + (size_t)h3 * H_;
    float4 w0 = *(const float4*)(wr + 4 * l);
    float4 w1 = *(const float4*)(wr + 256 + 4 * l);
    float bias = b_hh[h3];
    for (int bb = 0; bb < B_; bb++) {
        const float* pr = smemF + bb * H_;
        float4 s0 = *(const float4*)(pr + 4 * l);
        float4 s1 = *(const float4*)(pr + 256 + 4 * l);
        float p = w0.x * s0.x + w0.y * s0.y + w0.z * s0.z + w0.w * s0.w
                + w1.x * s1.x + w1.y * s1.y + w1.z * s1.z + w1.w * s1.w;
#pragma unroll
        for (int off = 32; off >= 1; off >>= 1) p += __shfl_xor(p, off, 64);
        if (l == 0) gh[bb * G3_ + h3] = p + bias;
    }
}

// ---------------- GRU gates -> state ----------------
__global__ void k_gate(const float* gi, const float* gh, const float* prev_eff,
                       float* state, float* out_state) {
    int idx = blockIdx.x * 256 + threadIdx.x;   // 16384 exact
    int b = idx >> 9, h = idx & 511;
    float ir = gi[b * G3_ + h],           hr = gh[b * G3_ + h];
    float iz = gi[b * G3_ + H_ + h],      hz = gh[b * G3_ + H_ + h];
    float in_ = gi[b * G3_ + 2 * H_ + h], hn = gh[b * G3_ + 2 * H_ + h];
    float r = 1.0f / (1.0f + expf(-(ir + hr)));
    float z = 1.0f / (1.0f + expf(-(iz + hz)));
    float n = tanhf(in_ + r * hn);
    float st = (1.0f - z) * n + z * prev_eff[idx];
    state[idx] = st;
    out_state[idx] = st;
}

// ---------------- score_g = state @ Wo_w.T + Wo_b via MFMA ----------------
__global__ void __launch_bounds__(256) k_scoreg(const float* state, const float* Wo_w,
                                                const float* Wo_b, float* scoreg) {
    __shared__ unsigned short Abf[32 * 520];
    int t = threadIdx.x;
    {
        int m = t & 31, g = t >> 5;                 // 32 rows x 8 col-groups of 64
        const float4* src = (const float4*)(state + m * 512 + g * 64);
        unsigned short* dst = &Abf[m * 520 + g * 64];
#pragma unroll
        for (int i = 0; i < 16; i++) {
            float4 v = src[i];
            ushort4 p; p.x = f2bf(v.x); p.y = f2bf(v.y); p.z = f2bf(v.z); p.w = f2bf(v.w);
            *(ushort4*)(dst + i * 4) = p;
        }
    }
    __syncthreads();
    int w = t >> 6, l = t & 63;
    int q = l >> 4, m16 = l & 15;
    int n = blockIdx.x * 64 + w * 16 + m16;
    const uint4* wrow = (const uint4*)(Wo_w + (size_t)n * 512 + q * 8);
    f32x4 acc0 = {0.f, 0.f, 0.f, 0.f}, acc1 = {0.f, 0.f, 0.f, 0.f};
#pragma unroll
    for (int kt = 0; kt < 16; kt++) {
        uint4 w0 = wrow[kt * 8];
        uint4 w1 = wrow[kt * 8 + 1];
        int4 pb;
        pb.x = (int)pkbf(w0.x, w0.y); pb.y = (int)pkbf(w0.z, w0.w);
        pb.z = (int)pkbf(w1.x, w1.y); pb.w = (int)pkbf(w1.z, w1.w);
        bf16x8 bv = *(bf16x8*)&pb;
        bf16x8 a0 = *(const bf16x8*)&Abf[m16 * 520 + kt * 32 + q * 8];
        bf16x8 a1 = *(const bf16x8*)&Abf[(16 + m16) * 520 + kt * 32 + q * 8];
        acc0 = __builtin_amdgcn_mfma_f32_16x16x32_bf16(a0, bv, acc0, 0, 0, 0);
        acc1 = __builtin_amdgcn_mfma_f32_16x16x32_bf16(a1, bv, acc1, 0, 0, 0);
    }
    float wb = Wo_b[n];
#pragma unroll
    for (int r = 0; r < 4; r++) {
        scoreg[(q * 4 + r) * V_ + n]        = acc0[r] + wb;
        scoreg[(16 + q * 4 + r) * V_ + n]   = acc1[r] + wb;
    }
}

// ---------------- fused partial score_c: atomicAdd_h tanh(enc@Wc_w.T + b)*state ----------------
// grid: 32 b * 8 s-tiles(128) * 2 h-halves(256), block 256 thr (4 waves).
// Wave w: all 8 s-subtiles x 4 h-tiles (h = (hh*16 + w*4 + jj)*16 + m).
// LDS A double-buffered, 64B rows, XOR chunk swizzle -> conflict-free b128 r/w.
__global__ void __launch_bounds__(256) k_sc(
    const float* encoded, const float* bin, const unsigned short* bpack,
    const float* Wc_b, const float* state, float* scorec) {
    __shared__ unsigned short Abuf[2][4096];    // 128 rows x 32 ushort (4 chunks of 8)
    __shared__ float partL[4][128];
    int t = threadIdx.x;
    int b  = blockIdx.x >> 4;
    int s0 = ((blockIdx.x >> 1) & 7) << 7;      // *128
    int hh = blockIdx.x & 1;
    int w = t >> 6, l = t & 63;
    int q = l >> 4, m = l & 15;

    // staging mapping: thread t -> row r, chunks {h2, h2+2} (write-bank-friendly split)
    int r   = t >> 1;
    int cq0 = t & 1;
    int cq1 = cq0 + 2;
    const uint4* encp = (const uint4*)(encoded + ((size_t)(b * S_ + s0 + r)) * 1024);
    unsigned int binu = __float_as_uint(bin[b * S_ + s0 + r]);
    int wro0 = r * 32 + ((cq0 ^ (r & 3)) << 3);
    int wro1 = r * 32 + ((cq1 ^ (r & 3)) << 3);

    f32x4 acc[8][4];
#pragma unroll
    for (int i = 0; i < 8; i++)
#pragma unroll
        for (int j = 0; j < 4; j++) { acc[i][j][0]=0.f; acc[i][j][1]=0.f; acc[i][j][2]=0.f; acc[i][j][3]=0.f; }

    // prologue: stage kt=0
    {
        uint4 a0 = encp[cq0 * 2], a1 = encp[cq0 * 2 + 1];
        uint4 b0 = encp[cq1 * 2], b1 = encp[cq1 * 2 + 1];
        *(uint4*)&Abuf[0][wro0] = pack4(a0, a1);
        *(uint4*)&Abuf[0][wro1] = pack4(b0, b1);
    }
    const unsigned short* bvbase = bpack + ((size_t)((hh * 16 + w * 4) * 64 + l)) * 8;
    __syncthreads();
    bf16x8 bv[4];
#pragma unroll
    for (int jj = 0; jj < 4; jj++) bv[jj] = *(const bf16x8*)(bvbase + jj * 512);

#pragma unroll 2
    for (int kt = 0; kt < NKT_; kt++) {
        int cur = kt & 1;
        // prefetch next enc tile (regs) - consumed after the MFMA block
        uint4 na0, na1, nb0, nb1;
        if (kt + 1 < 32) {
            na0 = encp[(kt + 1) * 8 + cq0 * 2]; na1 = encp[(kt + 1) * 8 + cq0 * 2 + 1];
            nb0 = encp[(kt + 1) * 8 + cq1 * 2]; nb1 = encp[(kt + 1) * 8 + cq1 * 2 + 1];
        }
        // prefetch next bv (regs)
        bf16x8 bvn[4];
        if (kt + 1 < NKT_) {
#pragma unroll
            for (int jj = 0; jj < 4; jj++)
                bvn[jj] = *(const bf16x8*)(bvbase + (size_t)(kt + 1) * 16384 + jj * 512);
        }
        // compute on current buffer
#pragma unroll
        for (int st = 0; st < 8; st++) {
            bf16x8 a = *(const bf16x8*)&Abuf[cur][(st * 16 + m) * 32 + ((q ^ (m & 3)) << 3)];
#pragma unroll
            for (int jj = 0; jj < 4; jj++)
                acc[st][jj] = __builtin_amdgcn_mfma_f32_16x16x32_bf16(a, bv[jj], acc[st][jj], 0, 0, 0);
        }
        // stage next tile into the other buffer
        if (kt + 1 < NKT_) {
            uint4 p0, p1;
            if (kt + 1 < 32) { p0 = pack4(na0, na1); p1 = pack4(nb0, nb1); }
            else {
                p0 = pack_bin(binu, (kt + 1) * 32 + cq0 * 8);
                p1 = pack_bin(binu, (kt + 1) * 32 + cq1 * 8);
            }
            *(uint4*)&Abuf[cur ^ 1][wro0] = p0;
            *(uint4*)&Abuf[cur ^ 1][wro1] = p1;
        }
        __syncthreads();
#pragma unroll
        for (int jj = 0; jj < 4; jj++) bv[jj] = bvn[jj];
    }

    // epilogue: partial val(s) = sum_{h in this half} tanh(sc+bias)*state
    float hb[4], hs[4];
#pragma unroll
    for (int jj = 0; jj < 4; jj++) {
        int h = (hh * 16 + w * 4 + jj) * 16 + m;
        hb[jj] = Wc_b[h];
        hs[jj] = state[b * H_ + h];
    }
#pragma unroll
    for (int st = 0; st < 8; st++) {
#pragma unroll
        for (int rr = 0; rr < 4; rr++) {
            float val = 0.f;
#pragma unroll
            for (int jj = 0; jj < 4; jj++)
                val += tanh_fast(acc[st][jj][rr] + hb[jj]) * hs[jj];
            val += __shfl_xor(val, 1, 64);
            val += __shfl_xor(val, 2, 64);
            val += __shfl_xor(val, 4, 64);
            val += __shfl_xor(val, 8, 64);
            if (m == 0) partL[w][st * 16 + q * 4 + rr] = val;
        }
    }
    __syncthreads();
    if (t < 128) {
        float tot = partL[0][t] + partL[1][t] + partL[2][t] + partL[3][t];
        atomicAdd(&scorec[b * 1024 + s0 + t], tot);
    }
}

// ---------------- exp pass + partial sums; c==16 finishes score_c (tanh+mask) ----------------
__global__ void k_exp(float* scoreg, float* scorec, const int* enc_idx,
                      float* partA, float* partC) {
    int blk = blockIdx.x;                       // 544 = 32 b * 17 chunks
    int b = blk / 17, c = blk % 17;
    int t = threadIdx.x;
    float sa = 0.f;
    if (c < 16) {
        int base = b * V_ + c * 2000;
        for (int i = t; i < 2000; i += 256) {
            float e = __expf(scoreg[base + i]);
            scoreg[base + i] = e;
            sa += e;
        }
    } else {
        int base = b * 1024;
        for (int i = t; i < 1024; i += 256) {
            float v = scorec[base + i];
            float s = tanh_fast(v) + (enc_idx[base + i] == 0 ? -1000.0f : 0.0f);
            float e = __expf(s);
            scorec[base + i] = e;
            sa += e;
        }
    }
#pragma unroll
    for (int off = 32; off >= 1; off >>= 1) sa += __shfl_xor(sa, off, 64);
    __shared__ float rA[4];
    int w = t >> 6, l = t & 63;
    if (l == 0) rA[w] = sa;
    __syncthreads();
    if (t == 0) {
        float tot = rA[0] + rA[1] + rA[2] + rA[3];
        partA[blk] = tot;
        if (c == 16) partC[b] = tot;
    }
}

// ---------------- combine: row sums, global c-sum, match count/list ----------------
__global__ void k_combine(const float* partA, const float* partC, float* rowinv, float* invgc,
                          int* cnt, int* list, const int* enc_idx, const int* input_idx) {
    __shared__ float rs[32], rc[32];
    int t = threadIdx.x;
    if (t < 32) {
        float a = 0.f;
        for (int j = 0; j < 17; j++) a += partA[t * 17 + j];
        rs[t] = a; rc[t] = partC[t];
        rowinv[t] = 1.0f / a;
        cnt[t] = 0;
    }
    __syncthreads();
    if (t == 0) {
        float g = 0.f;
        for (int b = 0; b < 32; b++) g += rc[b] / rs[b];
        invgc[0] = 1.0f / g;
    }
    for (int i = t; i < B_ * S_; i += 512) {
        int b = i >> 10;
        if (enc_idx[i] == input_idx[b]) {
            int p = atomicAdd(&cnt[b], 1);
            list[b * S_ + p] = i & 1023;
        }
    }
}

// ---------------- normalize: prob_g -> out, prob_c -> ws, OOV fill ----------------
__global__ void k_write(const float* scoreg, const float* scorec, const float* rowinv,
                        float* out, float* probc) {
    int idx = blockIdx.x * 256 + threadIdx.x;
    if (idx < B_ * V_) {
        int b = idx / V_, v = idx - b * V_;
        out[b * VO_ + v] = scoreg[idx] * rowinv[b];
    } else if (idx < B_ * V_ + B_ * S_) {
        int j = idx - B_ * V_;
        int b = j >> 10;
        probc[j] = scorec[j] * rowinv[b];
    } else {
        int j = idx - B_ * V_ - B_ * S_;
        if (j < B_ * 12) {
            int b = j / 12;
            out[b * VO_ + V_ + (j - b * 12)] = 0.0001f;
        }
    }
}

// ---------------- scatter prob_c into out ----------------
__global__ void k_scatter(const float* probc, const int* enc_idx, float* out) {
    int idx = blockIdx.x * 256 + threadIdx.x;   // 32768 exact
    int b = idx >> 10;
    atomicAdd(&out[b * VO_ + enc_idx[idx]], probc[idx]);
}

// ---------------- weighted_out via sparse match list ----------------
__global__ void k_wo(const float* probc, const int* list, const int* cnt, const float* invgc,
                     const float* encoded, const float* bin, float* out2) {
    int b = blockIdx.x, t = threadIdx.x;
    __shared__ float aL[1024];
    __shared__ int   sL[1024];
    int n = cnt[b];
    float scale = invgc[0] * (n > 1 ? 1.0f / (float)n : 1.0f);
    for (int i = t; i < n; i += 256) {
        int s = list[b * S_ + i];
        sL[i] = s;
        aL[i] = probc[b * S_ + s] * scale;
    }
    __syncthreads();
    for (int d = t; d < D2_; d += 256) {
        float acc = 0.f;
        for (int i = 0; i < n; i++) {
            int s = sL[i];
            float ev = (d < 1024) ? encoded[((size_t)(b * S_ + s)) * 1024 + d] : bin[b * S_ + s];
            acc += aL[i] * ev;
        }
        out2[b * D2_ + d] = acc;
    }
}

extern "C" void kernel_launch(void* const* d_in, const int* in_sizes, int n_in,
                              void* d_out, int out_size, void* d_ws, size_t ws_size,
                              hipStream_t stream) {
    const int*   input_idx = (const int*)d_in[0];
    const float* encoded   = (const float*)d_in[1];
    const int*   enc_idx   = (const int*)d_in[2];
    const float* prev      = (const float*)d_in[3];
    const float* weighted  = (const float*)d_in[4];
    const float* bin       = (const float*)d_in[5];
    const int*   order     = (const int*)d_in[6];
    const float* embed     = (const float*)d_in[7];
    const float* W_ih      = (const float*)d_in[8];
    const float* b_ih      = (const float*)d_in[9];
    const float* W_hh      = (const float*)d_in[10];
    const float* b_hh      = (const float*)d_in[11];
    const float* Wo_w      = (const float*)d_in[12];
    const float* Wo_b      = (const float*)d_in[13];
    const float* Wc_w      = (const float*)d_in[14];
    const float* Wc_b      = (const float*)d_in[15];
    const float* Ws_w      = (const float*)d_in[16];
    const float* Ws_b      = (const float*)d_in[17];

    float* out  = (float*)d_out;
    float* out1 = out + B_ * VO_;             // state
    float* out2 = out1 + B_ * H_;             // weighted_out

    float* ws_f     = (float*)d_ws;
    float* w_state  = ws_f;                   // 16384
    float* w_prev   = ws_f + 16384;           // 16384
    float* w_weff   = ws_f + 32768;           // 35968
    float* w_x      = ws_f + 68736;           // 45056
    float* w_gi     = ws_f + 113792;          // 49152
    float* w_gh     = ws_f + 162944;          // 49152
    float* w_scoreg = ws_f + 212096;          // 1024000
    float* w_scorec = ws_f + 1236096;         // 32768
    float* w_probc  = ws_f + 1268864;         // 32768
    float* w_partA  = ws_f + 1301632;         // 544
    float* w_partC  = ws_f + 1302176;         // 32
    float* w_rowinv = ws_f + 1302208;         // 32
    float* w_invgc  = ws_f + 1302240;         // 1 (+7 pad)
    int*   w_cnt    = (int*)(ws_f + 1302248); // 32
    int*   w_list   = w_cnt + 32;             // 32768
    unsigned short* w_bpack = (unsigned short*)(ws_f + 1335048); // 589824 ushort, 16B-aligned

    k_prep0<<<32, 256, 0, stream>>>(order, prev, weighted, encoded, bin, Ws_w, Ws_b, w_prev, w_weff);
    k_build_x<<<176, 256, 0, stream>>>(input_idx, embed, w_weff, w_x);
    k_pack_wc<<<2304, 256, 0, stream>>>(Wc_w, w_bpack);
    k_gi<<<768, 256, 16 * INP_ * sizeof(float), stream>>>(w_x, W_ih, b_ih, w_gi);
    k_gh<<<384, 256, B_ * H_ * sizeof(float), stream>>>(w_prev, W_hh, b_hh, w_gh);
    k_gate<<<64, 256, 0, stream>>>(w_gi, w_gh, w_prev, w_state, out1);
    hipMemsetAsync(w_scorec, 0, B_ * S_ * sizeof(float), stream);
    k_scoreg<<<500, 256, 0, stream>>>(w_state, Wo_w, Wo_b, w_scoreg);
    k_sc<<<512, 256, 0, stream>>>(encoded, bin, w_bpack, Wc_b, w_state, w_scorec);
    k_exp<<<544, 256, 0, stream>>>(w_scoreg, w_scorec, enc_idx, w_partA, w_partC);
    k_combine<<<1, 512, 0, stream>>>(w_partA, w_partC, w_rowinv, w_invgc, w_cnt, w_list, enc_idx, input_idx);
    k_write<<<4130, 256, 0, stream>>>(w_scoreg, w_scorec, w_rowinv, out, w_probc);
    k_scatter<<<128, 256, 0, stream>>>(w_probc, enc_idx, out);
    k_wo<<<32, 256, 0, stream>>>(w_probc, w_list, w_cnt, w_invgc, encoded, bin, out2);
}

// Round 4
// 440.381 us; speedup vs baseline: 1.0597x; 1.0597x over previous
//
#include <hip/hip_runtime.h>

#define B_   32
#define S_   1024
#define V_   32000
#define E_   256
#define H_   512
#define D2_  1124
#define IN_  1380
#define INP_ 1408
#define G3_  1536
#define VO_  32012   // V + MAX_OOVS
#define NKT_ 36      // K tiles of 32 covering 1152 (1124 padded)

typedef __bf16 bf16x8 __attribute__((ext_vector_type(8)));
typedef float  f32x4  __attribute__((ext_vector_type(4)));

static __device__ __forceinline__ unsigned short f2bf(float f) {
    union { float f; unsigned int u; } v; v.f = f;
    unsigned int u = v.u;
    unsigned int r = (u + 0x7FFFu + ((u >> 16) & 1u)) >> 16;  // RNE
    return (unsigned short)r;
}

// pack two f32 (as u32 bits) into two bf16 (round half up)
static __device__ __forceinline__ unsigned int pkbf(unsigned int a, unsigned int b) {
    return ((a + 0x8000u) >> 16) | ((b + 0x8000u) & 0xffff0000u);
}

// tanh via hw exp2/rcp: tanh(x) = 1 - 2/(e^{2x}+1); rel err ~1e-7
static __device__ __forceinline__ float tanh_fast(float x) {
    float e = __builtin_amdgcn_exp2f(x * 2.8853901817f);   // e^{2x}
    return 1.0f - 2.0f * __builtin_amdgcn_rcpf(e + 1.0f);
}

// async global->LDS, 16B per lane; lds base must be wave-uniform
static __device__ __forceinline__ void glds16(const void* g, void* l) {
    __builtin_amdgcn_global_load_lds(
        (const __attribute__((address_space(1))) unsigned int*)g,
        (__attribute__((address_space(3))) unsigned int*)l, 16, 0, 0);
}

// ---------------- fused prep: x = [emb, order? weighted : 0, pad], prev_eff ----------------
__global__ void k_prep(const int* order, const int* input_idx, const float* embed,
                       const float* weighted, const float* prev,
                       const float* encoded, const float* bin,
                       const float* Ws_w, const float* Ws_b,
                       float* x, float* prev_eff) {
    int b = blockIdx.x, t = threadIdx.x;
    int ord = order[0];
    const float* emb = embed + (size_t)input_idx[b] * E_;
    for (int d = t; d < INP_; d += 256) {
        float v;
        if (d < E_)       v = emb[d];
        else if (d < IN_) v = ord ? weighted[b * D2_ + (d - E_)] : 0.0f;
        else              v = 0.0f;
        x[b * INP_ + d] = v;
    }
    if (ord) {
        for (int i = t; i < H_; i += 256) prev_eff[b * H_ + i] = prev[b * H_ + i];
    } else {
        const float* encrow = encoded + ((size_t)(b * S_ + (S_ - 1))) * 1024;
        float bv = bin[b * S_ + (S_ - 1)];
        for (int h = t; h < H_; h += 256) {
            float acc = Ws_b[h];
            const float* wr = Ws_w + (size_t)h * D2_;
            for (int d = 0; d < 1024; d++) acc += encrow[d] * wr[d];
            for (int d = 1024; d < D2_; d++) acc += bv * wr[d];
            prev_eff[b * H_ + h] = acc;
        }
    }
}

// ---------------- pack Wc_w into MFMA B-fragment layout (bf16) ----------------
// bpack[((kt*32 + ht)*64 + lane)*8 + j] = Wc_w[ht*16 + (lane&15)][kt*32 + (lane>>4)*8 + j]
__global__ void k_pack_wc(const float* Wc_w, unsigned short* bpack) {
    int idx = blockIdx.x * 256 + threadIdx.x;   // 589824 exact
    int j = idx & 7, lane = (idx >> 3) & 63, ht = (idx >> 9) & 31, kt = idx >> 14;
    int h = ht * 16 + (lane & 15);
    int k = kt * 32 + (lane >> 4) * 8 + j;
    float v = (k < D2_) ? Wc_w[(size_t)h * D2_ + k] : 0.0f;
    bpack[idx] = f2bf(v);
}

// ---------------- gi = x @ W_ih.T + b_ih ----------------
__global__ void k_gi(const float* x, const float* W_ih, const float* b_ih, float* gi) {
    extern __shared__ float smemF[];            // 16 * 1408 floats
    int t = threadIdx.x;
    int bh = blockIdx.x & 1;
    int hq = blockIdx.x >> 1;
    const float4* xg = (const float4*)(x + (size_t)bh * 16 * INP_);
    float4* xl4 = (float4*)smemF;
    for (int j = t; j < 16 * INP_ / 4; j += 256) xl4[j] = xg[j];
    __syncthreads();
    int w = t >> 6, l = t & 63;
    int h3 = hq * 4 + w;
    const float* wr = W_ih + (size_t)h3 * IN_;
    float4 wv[6];
#pragma unroll
    for (int i = 0; i < 6; i++) {
        int k = 4 * l + 256 * i;
        if (k + 3 < IN_) wv[i] = *(const float4*)(wr + k);
        else {
            float a0 = (k     < IN_) ? wr[k]     : 0.f;
            float a1 = (k + 1 < IN_) ? wr[k + 1] : 0.f;
            float a2 = (k + 2 < IN_) ? wr[k + 2] : 0.f;
            float a3 = (k + 3 < IN_) ? wr[k + 3] : 0.f;
            wv[i] = make_float4(a0, a1, a2, a3);
        }
    }
    float bias = b_ih[h3];
    for (int bb = 0; bb < 16; bb++) {
        const float4* xr = xl4 + bb * (INP_ / 4);
        float p = 0.f;
#pragma unroll
        for (int i = 0; i < 6; i++) {
            float4 xv = xr[l + 64 * i];
            p += wv[i].x * xv.x + wv[i].y * xv.y + wv[i].z * xv.z + wv[i].w * xv.w;
        }
#pragma unroll
        for (int off = 32; off >= 1; off >>= 1) p += __shfl_xor(p, off, 64);
        if (l == 0) gi[(bh * 16 + bb) * G3_ + h3] = p + bias;
    }
}

// ---------------- gh = prev_eff @ W_hh.T + b_hh ----------------
__global__ void k_gh(const float* prev_eff, const float* W_hh, const float* b_hh, float* gh) {
    extern __shared__ float smemF[];            // 32*512 floats
    int t = threadIdx.x;
    const float4* pg = (const float4*)prev_eff;
    float4* pl4 = (float4*)smemF;
    for (int j = t; j < B_ * H_ / 4; j += 256) pl4[j] = pg[j];
    __syncthreads();
    int w = t >> 6, l = t & 63;
    int h3 = blockIdx.x * 4 + w;
    const float* wr = W_hh + (size_t)h3 * H_;
    float4 w0 = *(const float4*)(wr + 4 * l);
    float4 w1 = *(const float4*)(wr + 256 + 4 * l);
    float bias = b_hh[h3];
    for (int bb = 0; bb < B_; bb++) {
        const float* pr = smemF + bb * H_;
        float4 s0 = *(const float4*)(pr + 4 * l);
        float4 s1 = *(const float4*)(pr + 256 + 4 * l);
        float p = w0.x * s0.x + w0.y * s0.y + w0.z * s0.z + w0.w * s0.w
                + w1.x * s1.x + w1.y * s1.y + w1.z * s1.z + w1.w * s1.w;
#pragma unroll
        for (int off = 32; off >= 1; off >>= 1) p += __shfl_xor(p, off, 64);
        if (l == 0) gh[bb * G3_ + h3] = p + bias;
    }
}

// ---------------- GRU gates -> state ----------------
__global__ void k_gate(const float* gi, const float* gh, const float* prev_eff,
                       float* state, float* out_state) {
    int idx = blockIdx.x * 256 + threadIdx.x;   // 16384 exact
    int b = idx >> 9, h = idx & 511;
    float ir = gi[b * G3_ + h],           hr = gh[b * G3_ + h];
    float iz = gi[b * G3_ + H_ + h],      hz = gh[b * G3_ + H_ + h];
    float in_ = gi[b * G3_ + 2 * H_ + h], hn = gh[b * G3_ + 2 * H_ + h];
    float r = 1.0f / (1.0f + expf(-(ir + hr)));
    float z = 1.0f / (1.0f + expf(-(iz + hz)));
    float n = tanhf(in_ + r * hn);
    float st = (1.0f - z) * n + z * prev_eff[idx];
    state[idx] = st;
    out_state[idx] = st;
}

// ---------------- score_g = state @ Wo_w.T + Wo_b via MFMA ----------------
__global__ void __launch_bounds__(256) k_scoreg(const float* state, const float* Wo_w,
                                                const float* Wo_b, float* scoreg) {
    __shared__ unsigned short Abf[32 * 520];
    int t = threadIdx.x;
    {
        int m = t & 31, g = t >> 5;                 // 32 rows x 8 col-groups of 64
        const float4* src = (const float4*)(state + m * 512 + g * 64);
        unsigned short* dst = &Abf[m * 520 + g * 64];
#pragma unroll
        for (int i = 0; i < 16; i++) {
            float4 v = src[i];
            ushort4 p; p.x = f2bf(v.x); p.y = f2bf(v.y); p.z = f2bf(v.z); p.w = f2bf(v.w);
            *(ushort4*)(dst + i * 4) = p;
        }
    }
    __syncthreads();
    int w = t >> 6, l = t & 63;
    int q = l >> 4, m16 = l & 15;
    int n = blockIdx.x * 64 + w * 16 + m16;
    const uint4* wrow = (const uint4*)(Wo_w + (size_t)n * 512 + q * 8);
    f32x4 acc0 = {0.f, 0.f, 0.f, 0.f}, acc1 = {0.f, 0.f, 0.f, 0.f};
#pragma unroll
    for (int kt = 0; kt < 16; kt++) {
        uint4 w0 = wrow[kt * 8];
        uint4 w1 = wrow[kt * 8 + 1];
        int4 pb;
        pb.x = (int)pkbf(w0.x, w0.y); pb.y = (int)pkbf(w0.z, w0.w);
        pb.z = (int)pkbf(w1.x, w1.y); pb.w = (int)pkbf(w1.z, w1.w);
        bf16x8 bv = *(bf16x8*)&pb;
        bf16x8 a0 = *(const bf16x8*)&Abf[m16 * 520 + kt * 32 + q * 8];
        bf16x8 a1 = *(const bf16x8*)&Abf[(16 + m16) * 520 + kt * 32 + q * 8];
        acc0 = __builtin_amdgcn_mfma_f32_16x16x32_bf16(a0, bv, acc0, 0, 0, 0);
        acc1 = __builtin_amdgcn_mfma_f32_16x16x32_bf16(a1, bv, acc1, 0, 0, 0);
    }
    float wb = Wo_b[n];
#pragma unroll
    for (int r = 0; r < 4; r++) {
        scoreg[(q * 4 + r) * V_ + n]        = acc0[r] + wb;
        scoreg[(16 + q * 4 + r) * V_ + n]   = acc1[r] + wb;
    }
}

// ---------------- fused score_c = tanh(sum_h tanh(enc@Wc_w.T+b)*state) + mask ----------------
// grid: 32 b * 16 s-tiles(64) = 512 blocks, 512 thr (8 waves).
// Block tile: 64 s x 512 h; wave w: 64 s x 64 h (4x4 accs of 16x16x32).
// B (bpack, frag-ordered bf16) staged via global_load_lds; A (enc f32) packed in VALU.
// Double-buffered, ONE barrier per K-step.
__global__ void __launch_bounds__(512) k_sc(
    const float* encoded, const float* bin, const unsigned short* bpack,
    const float* Wc_b, const float* state, const int* enc_idx, float* scorec) {
    __shared__ unsigned short Ab[2][2048];      // 64 s-rows x 32 k
    __shared__ unsigned short Bb[2][16384];     // 32 ht x 64 lanes x 8 (mirror of bpack slice)
    __shared__ float partL[8][64];
    int t = threadIdx.x;
    int b  = blockIdx.x >> 4;
    int s0 = (blockIdx.x & 15) << 6;
    int w = t >> 6, l = t & 63;
    int q = l >> 4, m = l & 15;

    // A staging: thread t -> row ar (0..63), k-offset ak
    int ar = t >> 3, ak = (t & 7) * 4;
    const float* encrow = encoded + ((size_t)(b * S_ + s0 + ar)) * 1024 + ak;
    float binf = bin[b * S_ + s0 + ar];

    f32x4 acc[4][4];
#pragma unroll
    for (int i = 0; i < 4; i++)
#pragma unroll
        for (int j = 0; j < 4; j++) { acc[i][j][0]=0.f; acc[i][j][1]=0.f; acc[i][j][2]=0.f; acc[i][j][3]=0.f; }

    // prologue: stage kt=0 (A pack + B glds), prefetch A kt=1
    {
        float4 a0 = *(const float4*)encrow;
        ushort4 p; p.x = f2bf(a0.x); p.y = f2bf(a0.y); p.z = f2bf(a0.z); p.w = f2bf(a0.w);
        *(ushort4*)&Ab[0][ar * 32 + ak] = p;
#pragma unroll
        for (int i = 0; i < 4; i++)
            glds16(bpack + (size_t)((i * 8 + w) * 64 + l) * 8, &Bb[0][(i * 8 + w) * 512]);
    }
    float4 a1 = *(const float4*)(encrow + 32);
    __syncthreads();

#pragma unroll 2
    for (int kt = 0; kt < NKT_; kt++) {
        int cur = kt & 1;
        if (kt + 1 < NKT_) {
            int nx = cur ^ 1;
#pragma unroll
            for (int i = 0; i < 4; i++)
                glds16(bpack + (size_t)(kt + 1) * 16384 + (size_t)((i * 8 + w) * 64 + l) * 8,
                       &Bb[nx][(i * 8 + w) * 512]);
            ushort4 pn;
            if (kt + 1 < 32) {
                pn.x = f2bf(a1.x); pn.y = f2bf(a1.y); pn.z = f2bf(a1.z); pn.w = f2bf(a1.w);
            } else {
                int kb = (kt + 1) * 32 + ak;
                pn.x = f2bf(kb     < D2_ ? binf : 0.f);
                pn.y = f2bf(kb + 1 < D2_ ? binf : 0.f);
                pn.z = f2bf(kb + 2 < D2_ ? binf : 0.f);
                pn.w = f2bf(kb + 3 < D2_ ? binf : 0.f);
            }
            *(ushort4*)&Ab[nx][ar * 32 + ak] = pn;
            if (kt + 2 < 32) a1 = *(const float4*)(encrow + (kt + 2) * 32);
        }
        bf16x8 av[4], bv[4];
#pragma unroll
        for (int st = 0; st < 4; st++)
            av[st] = *(const bf16x8*)&Ab[cur][(st * 16 + m) * 32 + q * 8];
#pragma unroll
        for (int jj = 0; jj < 4; jj++)
            bv[jj] = *(const bf16x8*)&Bb[cur][((w * 4 + jj) * 64 + l) * 8];
#pragma unroll
        for (int st = 0; st < 4; st++)
#pragma unroll
            for (int jj = 0; jj < 4; jj++)
                acc[st][jj] = __builtin_amdgcn_mfma_f32_16x16x32_bf16(av[st], bv[jj], acc[st][jj], 0, 0, 0);
        __syncthreads();
    }

    // epilogue: val(s) = sum_h tanh(sc + bias_h) * state_h over this wave's 64 h
    float hb[4], hs[4];
#pragma unroll
    for (int jj = 0; jj < 4; jj++) {
        int h = (w * 4 + jj) * 16 + m;
        hb[jj] = Wc_b[h];
        hs[jj] = state[b * H_ + h];
    }
#pragma unroll
    for (int st = 0; st < 4; st++) {
#pragma unroll
        for (int r = 0; r < 4; r++) {
            float val = 0.f;
#pragma unroll
            for (int jj = 0; jj < 4; jj++)
                val += tanh_fast(acc[st][jj][r] + hb[jj]) * hs[jj];
            val += __shfl_xor(val, 1, 64);
            val += __shfl_xor(val, 2, 64);
            val += __shfl_xor(val, 4, 64);
            val += __shfl_xor(val, 8, 64);
            if (m == 0) partL[w][st * 16 + q * 4 + r] = val;
        }
    }
    __syncthreads();
    if (t < 64) {
        float tot = 0.f;
#pragma unroll
        for (int ww = 0; ww < 8; ww++) tot += partL[ww][t];
        int s = s0 + t;
        int ei = enc_idx[b * S_ + s];
        scorec[b * S_ + s] = tanh_fast(tot) + (ei == 0 ? -1000.0f : 0.0f);
    }
}

// ---------------- exp pass + partial sums; c==16 handles score_c chunk ----------------
__global__ void k_exp(float* scoreg, float* scorec, float* partA, float* partC) {
    int blk = blockIdx.x;                       // 544 = 32 b * 17 chunks
    int b = blk / 17, c = blk % 17;
    int t = threadIdx.x;
    float sa = 0.f;
    if (c < 16) {
        int base = b * V_ + c * 2000;
        for (int i = t; i < 2000; i += 256) {
            float e = __expf(scoreg[base + i]);
            scoreg[base + i] = e;
            sa += e;
        }
    } else {
        int base = b * 1024;
        for (int i = t; i < 1024; i += 256) {
            float e = __expf(scorec[base + i]);
            scorec[base + i] = e;
            sa += e;
        }
    }
#pragma unroll
    for (int off = 32; off >= 1; off >>= 1) sa += __shfl_xor(sa, off, 64);
    __shared__ float rA[4];
    int w = t >> 6, l = t & 63;
    if (l == 0) rA[w] = sa;
    __syncthreads();
    if (t == 0) {
        float tot = rA[0] + rA[1] + rA[2] + rA[3];
        partA[blk] = tot;
        if (c == 16) partC[b] = tot;
    }
}

// ---------------- combine: row sums, global c-sum, match count/list ----------------
__global__ void k_combine(const float* partA, const float* partC, float* rowinv, float* invgc,
                          int* cnt, int* list, const int* enc_idx, const int* input_idx) {
    __shared__ float rs[32], rc[32];
    int t = threadIdx.x;
    if (t < 32) {
        float a = 0.f;
        for (int j = 0; j < 17; j++) a += partA[t * 17 + j];
        rs[t] = a; rc[t] = partC[t];
        rowinv[t] = 1.0f / a;
        cnt[t] = 0;
    }
    __syncthreads();
    if (t == 0) {
        float g = 0.f;
        for (int b = 0; b < 32; b++) g += rc[b] / rs[b];
        invgc[0] = 1.0f / g;
    }
    for (int i = t; i < B_ * S_; i += 512) {
        int b = i >> 10;
        if (enc_idx[i] == input_idx[b]) {
            int p = atomicAdd(&cnt[b], 1);
            list[b * S_ + p] = i & 1023;
        }
    }
}

// ---------------- normalize: prob_g -> out, prob_c -> ws, OOV fill ----------------
__global__ void k_write(const float* scoreg, const float* scorec, const float* rowinv,
                        float* out, float* probc) {
    int idx = blockIdx.x * 256 + threadIdx.x;
    if (idx < B_ * V_) {
        int b = idx / V_, v = idx - b * V_;
        out[b * VO_ + v] = scoreg[idx] * rowinv[b];
    } else if (idx < B_ * V_ + B_ * S_) {
        int j = idx - B_ * V_;
        int b = j >> 10;
        probc[j] = scorec[j] * rowinv[b];
    } else {
        int j = idx - B_ * V_ - B_ * S_;
        if (j < B_ * 12) {
            int b = j / 12;
            out[b * VO_ + V_ + (j - b * 12)] = 0.0001f;
        }
    }
}

// ---------------- scatter prob_c into out ----------------
__global__ void k_scatter(const float* probc, const int* enc_idx, float* out) {
    int idx = blockIdx.x * 256 + threadIdx.x;   // 32768 exact
    int b = idx >> 10;
    atomicAdd(&out[b * VO_ + enc_idx[idx]], probc[idx]);
}

// ---------------- weighted_out via sparse match list ----------------
__global__ void k_wo(const float* probc, const int* list, const int* cnt, const float* invgc,
                     const float* encoded, const float* bin, float* out2) {
    int b = blockIdx.x, t = threadIdx.x;
    __shared__ float aL[1024];
    __shared__ int   sL[1024];
    int n = cnt[b];
    float scale = invgc[0] * (n > 1 ? 1.0f / (float)n : 1.0f);
    for (int i = t; i < n; i += 256) {
        int s = list[b * S_ + i];
        sL[i] = s;
        aL[i] = probc[b * S_ + s] * scale;
    }
    __syncthreads();
    for (int d = t; d < D2_; d += 256) {
        float acc = 0.f;
        for (int i = 0; i < n; i++) {
            int s = sL[i];
            float ev = (d < 1024) ? encoded[((size_t)(b * S_ + s)) * 1024 + d] : bin[b * S_ + s];
            acc += aL[i] * ev;
        }
        out2[b * D2_ + d] = acc;
    }
}

extern "C" void kernel_launch(void* const* d_in, const int* in_sizes, int n_in,
                              void* d_out, int out_size, void* d_ws, size_t ws_size,
                              hipStream_t stream) {
    const int*   input_idx = (const int*)d_in[0];
    const float* encoded   = (const float*)d_in[1];
    const int*   enc_idx   = (const int*)d_in[2];
    const float* prev      = (const float*)d_in[3];
    const float* weighted  = (const float*)d_in[4];
    const float* bin       = (const float*)d_in[5];
    const int*   order     = (const int*)d_in[6];
    const float* embed     = (const float*)d_in[7];
    const float* W_ih      = (const float*)d_in[8];
    const float* b_ih      = (const float*)d_in[9];
    const float* W_hh      = (const float*)d_in[10];
    const float* b_hh      = (const float*)d_in[11];
    const float* Wo_w      = (const float*)d_in[12];
    const float* Wo_b      = (const float*)d_in[13];
    const float* Wc_w      = (const float*)d_in[14];
    const float* Wc_b      = (const float*)d_in[15];
    const float* Ws_w      = (const float*)d_in[16];
    const float* Ws_b      = (const float*)d_in[17];

    float* out  = (float*)d_out;
    float* out1 = out + B_ * VO_;             // state
    float* out2 = out1 + B_ * H_;             // weighted_out

    float* ws_f     = (float*)d_ws;
    float* w_state  = ws_f;                   // 16384
    float* w_prev   = ws_f + 16384;           // 16384
    float* w_x      = ws_f + 68736;           // 45056
    float* w_gi     = ws_f + 113792;          // 49152
    float* w_gh     = ws_f + 162944;          // 49152
    float* w_scoreg = ws_f + 212096;          // 1024000
    float* w_scorec = ws_f + 1236096;         // 32768
    float* w_probc  = ws_f + 1268864;         // 32768
    float* w_partA  = ws_f + 1301632;         // 544
    float* w_partC  = ws_f + 1302176;         // 32
    float* w_rowinv = ws_f + 1302208;         // 32
    float* w_invgc  = ws_f + 1302240;         // 1 (+7 pad)
    int*   w_cnt    = (int*)(ws_f + 1302248); // 32
    int*   w_list   = w_cnt + 32;             // 32768
    unsigned short* w_bpack = (unsigned short*)(ws_f + 1335048); // 589824 ushort, 16B-aligned

    k_prep<<<32, 256, 0, stream>>>(order, input_idx, embed, weighted, prev,
                                   encoded, bin, Ws_w, Ws_b, w_x, w_prev);
    k_pack_wc<<<2304, 256, 0, stream>>>(Wc_w, w_bpack);
    k_gi<<<768, 256, 16 * INP_ * sizeof(float), stream>>>(w_x, W_ih, b_ih, w_gi);
    k_gh<<<384, 256, B_ * H_ * sizeof(float), stream>>>(w_prev, W_hh, b_hh, w_gh);
    k_gate<<<64, 256, 0, stream>>>(w_gi, w_gh, w_prev, w_state, out1);
    k_scoreg<<<500, 256, 0, stream>>>(w_state, Wo_w, Wo_b, w_scoreg);
    k_sc<<<512, 512, 0, stream>>>(encoded, bin, w_bpack, Wc_b, w_state, enc_idx, w_scorec);
    k_exp<<<544, 256, 0, stream>>>(w_scoreg, w_scorec, w_partA, w_partC);
    k_combine<<<1, 512, 0, stream>>>(w_partA, w_partC, w_rowinv, w_invgc, w_cnt, w_list, enc_idx, input_idx);
    k_write<<<4130, 256, 0, stream>>>(w_scoreg, w_scorec, w_rowinv, out, w_probc);
    k_scatter<<<128, 256, 0, stream>>>(w_probc, enc_idx, out);
    k_wo<<<32, 256, 0, stream>>>(w_probc, w_list, w_cnt, w_invgc, encoded, bin, out2);
}

// Round 5
// 439.884 us; speedup vs baseline: 1.0609x; 1.0011x over previous
//
#include <hip/hip_runtime.h>

#define B_   32
#define S_   1024
#define V_   32000
#define E_   256
#define H_   512
#define D2_  1124
#define IN_  1380
#define INP_ 1408
#define G3_  1536
#define VO_  32012   // V + MAX_OOVS

typedef __bf16 bf16x8 __attribute__((ext_vector_type(8)));
typedef float  f32x4  __attribute__((ext_vector_type(4)));

static __device__ __forceinline__ unsigned short f2bf(float f) {
    union { float f; unsigned int u; } v; v.f = f;
    unsigned int u = v.u;
    unsigned int r = (u + 0x7FFFu + ((u >> 16) & 1u)) >> 16;  // RNE
    return (unsigned short)r;
}

// pack two f32 (as u32 bits) into two bf16 (round half up)
static __device__ __forceinline__ unsigned int pkbf(unsigned int a, unsigned int b) {
    return ((a + 0x8000u) >> 16) | ((b + 0x8000u) & 0xffff0000u);
}

// tanh via hw exp2/rcp: tanh(x) = 1 - 2/(e^{2x}+1); rel err ~1e-7
static __device__ __forceinline__ float tanh_fast(float x) {
    float e = __builtin_amdgcn_exp2f(x * 2.8853901817f);   // e^{2x}
    return 1.0f - 2.0f * __builtin_amdgcn_rcpf(e + 1.0f);
}

// ---------------- fused prep: x = [emb, order? weighted : 0, pad], prev_eff ----------------
__global__ void k_prep(const int* order, const int* input_idx, const float* embed,
                       const float* weighted, const float* prev,
                       const float* encoded, const float* bin,
                       const float* Ws_w, const float* Ws_b,
                       float* x, float* prev_eff) {
    int b = blockIdx.x, t = threadIdx.x;
    int ord = order[0];
    const float* emb = embed + (size_t)input_idx[b] * E_;
    for (int d = t; d < INP_; d += 256) {
        float v;
        if (d < E_)       v = emb[d];
        else if (d < IN_) v = ord ? weighted[b * D2_ + (d - E_)] : 0.0f;
        else              v = 0.0f;
        x[b * INP_ + d] = v;
    }
    if (ord) {
        for (int i = t; i < H_; i += 256) prev_eff[b * H_ + i] = prev[b * H_ + i];
    } else {
        const float* encrow = encoded + ((size_t)(b * S_ + (S_ - 1))) * 1024;
        float bv = bin[b * S_ + (S_ - 1)];
        for (int h = t; h < H_; h += 256) {
            float acc = Ws_b[h];
            const float* wr = Ws_w + (size_t)h * D2_;
            for (int d = 0; d < 1024; d++) acc += encrow[d] * wr[d];
            for (int d = 1024; d < D2_; d++) acc += bv * wr[d];
            prev_eff[b * H_ + h] = acc;
        }
    }
}

// ---------------- pack Wc_w into MFMA B-fragment layout (bf16) ----------------
// bpack[((kt*32 + ht)*64 + lane)*8 + j] = Wc_w[ht*16 + (lane&15)][kt*32 + (lane>>4)*8 + j]
__global__ void k_pack_wc(const float* Wc_w, unsigned short* bpack) {
    int idx = blockIdx.x * 256 + threadIdx.x;   // 589824 exact
    int j = idx & 7, lane = (idx >> 3) & 63, ht = (idx >> 9) & 31, kt = idx >> 14;
    int h = ht * 16 + (lane & 15);
    int k = kt * 32 + (lane >> 4) * 8 + j;
    float v = (k < D2_) ? Wc_w[(size_t)h * D2_ + k] : 0.0f;
    bpack[idx] = f2bf(v);
}

// ---------------- gi = x @ W_ih.T + b_ih ----------------
__global__ void k_gi(const float* x, const float* W_ih, const float* b_ih, float* gi) {
    extern __shared__ float smemF[];            // 16 * 1408 floats
    int t = threadIdx.x;
    int bh = blockIdx.x & 1;
    int hq = blockIdx.x >> 1;
    const float4* xg = (const float4*)(x + (size_t)bh * 16 * INP_);
    float4* xl4 = (float4*)smemF;
    for (int j = t; j < 16 * INP_ / 4; j += 256) xl4[j] = xg[j];
    __syncthreads();
    int w = t >> 6, l = t & 63;
    int h3 = hq * 4 + w;
    const float* wr = W_ih + (size_t)h3 * IN_;
    float4 wv[6];
#pragma unroll
    for (int i = 0; i < 6; i++) {
        int k = 4 * l + 256 * i;
        if (k + 3 < IN_) wv[i] = *(const float4*)(wr + k);
        else {
            float a0 = (k     < IN_) ? wr[k]     : 0.f;
            float a1 = (k + 1 < IN_) ? wr[k + 1] : 0.f;
            float a2 = (k + 2 < IN_) ? wr[k + 2] : 0.f;
            float a3 = (k + 3 < IN_) ? wr[k + 3] : 0.f;
            wv[i] = make_float4(a0, a1, a2, a3);
        }
    }
    float bias = b_ih[h3];
    for (int bb = 0; bb < 16; bb++) {
        const float4* xr = xl4 + bb * (INP_ / 4);
        float p = 0.f;
#pragma unroll
        for (int i = 0; i < 6; i++) {
            float4 xv = xr[l + 64 * i];
            p += wv[i].x * xv.x + wv[i].y * xv.y + wv[i].z * xv.z + wv[i].w * xv.w;
        }
#pragma unroll
        for (int off = 32; off >= 1; off >>= 1) p += __shfl_xor(p, off, 64);
        if (l == 0) gi[(bh * 16 + bb) * G3_ + h3] = p + bias;
    }
}

// ---------------- gh = prev_eff @ W_hh.T + b_hh ----------------
__global__ void k_gh(const float* prev_eff, const float* W_hh, const float* b_hh, float* gh) {
    extern __shared__ float smemF[];            // 32*512 floats
    int t = threadIdx.x;
    const float4* pg = (const float4*)prev_eff;
    float4* pl4 = (float4*)smemF;
    for (int j = t; j < B_ * H_ / 4; j += 256) pl4[j] = pg[j];
    __syncthreads();
    int w = t >> 6, l = t & 63;
    int h3 = blockIdx.x * 4 + w;
    const float* wr = W_hh + (size_t)h3 * H_;
    float4 w0 = *(const float4*)(wr + 4 * l);
    float4 w1 = *(const float4*)(wr + 256 + 4 * l);
    float bias = b_hh[h3];
    for (int bb = 0; bb < B_; bb++) {
        const float* pr = smemF + bb * H_;
        float4 s0 = *(const float4*)(pr + 4 * l);
        float4 s1 = *(const float4*)(pr + 256 + 4 * l);
        float p = w0.x * s0.x + w0.y * s0.y + w0.z * s0.z + w0.w * s0.w
                + w1.x * s1.x + w1.y * s1.y + w1.z * s1.z + w1.w * s1.w;
#pragma unroll
        for (int off = 32; off >= 1; off >>= 1) p += __shfl_xor(p, off, 64);
        if (l == 0) gh[bb * G3_ + h3] = p + bias;
    }
}

// ---------------- GRU gates -> state ----------------
__global__ void k_gate(const float* gi, const float* gh, const float* prev_eff,
                       float* state, float* out_state) {
    int idx = blockIdx.x * 256 + threadIdx.x;   // 16384 exact
    int b = idx >> 9, h = idx & 511;
    float ir = gi[b * G3_ + h],           hr = gh[b * G3_ + h];
    float iz = gi[b * G3_ + H_ + h],      hz = gh[b * G3_ + H_ + h];
    float in_ = gi[b * G3_ + 2 * H_ + h], hn = gh[b * G3_ + 2 * H_ + h];
    float r = 1.0f / (1.0f + expf(-(ir + hr)));
    float z = 1.0f / (1.0f + expf(-(iz + hz)));
    float n = tanhf(in_ + r * hn);
    float st = (1.0f - z) * n + z * prev_eff[idx];
    state[idx] = st;
    out_state[idx] = st;
}

// ---------------- score_g = state @ Wo_w.T + Wo_b via MFMA ----------------
__global__ void __launch_bounds__(256) k_scoreg(const float* state, const float* Wo_w,
                                                const float* Wo_b, float* scoreg) {
    __shared__ unsigned short Abf[32 * 520];
    int t = threadIdx.x;
    {
        int m = t & 31, g = t >> 5;                 // 32 rows x 8 col-groups of 64
        const float4* src = (const float4*)(state + m * 512 + g * 64);
        unsigned short* dst = &Abf[m * 520 + g * 64];
#pragma unroll
        for (int i = 0; i < 16; i++) {
            float4 v = src[i];
            ushort4 p; p.x = f2bf(v.x); p.y = f2bf(v.y); p.z = f2bf(v.z); p.w = f2bf(v.w);
            *(ushort4*)(dst + i * 4) = p;
        }
    }
    __syncthreads();
    int w = t >> 6, l = t & 63;
    int q = l >> 4, m16 = l & 15;
    int n = blockIdx.x * 64 + w * 16 + m16;
    const uint4* wrow = (const uint4*)(Wo_w + (size_t)n * 512 + q * 8);
    f32x4 acc0 = {0.f, 0.f, 0.f, 0.f}, acc1 = {0.f, 0.f, 0.f, 0.f};
#pragma unroll
    for (int kt = 0; kt < 16; kt++) {
        uint4 w0 = wrow[kt * 8];
        uint4 w1 = wrow[kt * 8 + 1];
        int4 pb;
        pb.x = (int)pkbf(w0.x, w0.y); pb.y = (int)pkbf(w0.z, w0.w);
        pb.z = (int)pkbf(w1.x, w1.y); pb.w = (int)pkbf(w1.z, w1.w);
        bf16x8 bv = *(bf16x8*)&pb;
        bf16x8 a0 = *(const bf16x8*)&Abf[m16 * 520 + kt * 32 + q * 8];
        bf16x8 a1 = *(const bf16x8*)&Abf[(16 + m16) * 520 + kt * 32 + q * 8];
        acc0 = __builtin_amdgcn_mfma_f32_16x16x32_bf16(a0, bv, acc0, 0, 0, 0);
        acc1 = __builtin_amdgcn_mfma_f32_16x16x32_bf16(a1, bv, acc1, 0, 0, 0);
    }
    float wb = Wo_b[n];
#pragma unroll
    for (int r = 0; r < 4; r++) {
        scoreg[(q * 4 + r) * V_ + n]        = acc0[r] + wb;
        scoreg[(16 + q * 4 + r) * V_ + n]   = acc1[r] + wb;
    }
}

// ---------------- fused score_c = tanh(sum_h tanh(enc@Wc_w.T+b)*state) + mask ----------------
// grid 512 = 32 b * 16 s-tiles(64); block 512 thr (8 waves); wave w: 64s x 64h (4x4 accs).
// K-loop: 9 stages of BK=128, ONE barrier per stage, double-buffered LDS A.
// A (enc f32) loaded to regs a full stage ahead, packed bf16 -> LDS (row stride 136: 2-way max).
// B frags read per-wave from L2-hot bpack inside the compute phase.
// Invariant: nothing is outstanding at any barrier -> no vmcnt(0) drain stalls.
__global__ void __launch_bounds__(512, 4) k_sc(
    const float* encoded, const float* bin, const unsigned short* bpack,
    const float* Wc_b, const float* state, const int* enc_idx, float* scorec) {
    __shared__ unsigned short Ab[2][64 * 136];  // 64 s-rows x 128 k (+8 pad)
    __shared__ float partL[8][64];
    int t = threadIdx.x;
    int b  = blockIdx.x >> 4;
    int s0 = (blockIdx.x & 15) << 6;
    int w = t >> 6, l = t & 63;
    int q = l >> 4, m = l & 15;

    // A staging: thread t -> row r (0..63), k-group kg (0..7 of 16 floats)
    int r = t >> 3, kg = t & 7;
    const float* encbase = encoded + ((size_t)(b * S_ + s0 + r)) * 1024 + kg * 16;
    float binf = bin[b * S_ + s0 + r];
    unsigned short* dst0 = &Ab[0][r * 136 + kg * 16];
    unsigned short* dst1 = &Ab[1][r * 136 + kg * 16];

    f32x4 acc[4][4];
#pragma unroll
    for (int i = 0; i < 4; i++)
#pragma unroll
        for (int j = 0; j < 4; j++) { acc[i][j][0]=0.f; acc[i][j][1]=0.f; acc[i][j][2]=0.f; acc[i][j][3]=0.f; }

    float4 ap[4];
#pragma unroll
    for (int j = 0; j < 4; j++) ap[j] = *(const float4*)(encbase + j * 4);

    for (int s = 0; s < 9; s++) {
        unsigned short* dst = (s & 1) ? dst1 : dst0;
        if (s < 8) {
#pragma unroll
            for (int j = 0; j < 4; j++) {
                ushort4 p;
                p.x = f2bf(ap[j].x); p.y = f2bf(ap[j].y);
                p.z = f2bf(ap[j].z); p.w = f2bf(ap[j].w);
                *(ushort4*)(dst + j * 4) = p;
            }
        } else {
#pragma unroll
            for (int j = 0; j < 4; j++) {
                int kb = kg * 16 + j * 4;       // local k; global k = 1024 + kb
                ushort4 p;
                p.x = f2bf(kb     < 100 ? binf : 0.f);
                p.y = f2bf(kb + 1 < 100 ? binf : 0.f);
                p.z = f2bf(kb + 2 < 100 ? binf : 0.f);
                p.w = f2bf(kb + 3 < 100 ? binf : 0.f);
                *(ushort4*)(dst + j * 4) = p;
            }
        }
        __syncthreads();                        // Ab[s&1] ready; nothing in flight
        if (s < 7) {
#pragma unroll
            for (int j = 0; j < 4; j++) ap[j] = *(const float4*)(encbase + (s + 1) * 128 + j * 4);
        }
        const unsigned short* abase = &Ab[s & 1][m * 136 + q * 8];
#pragma unroll
        for (int sub = 0; sub < 4; sub++) {
            int kt = s * 4 + sub;
            bf16x8 bv[4], av[4];
#pragma unroll
            for (int jj = 0; jj < 4; jj++)
                bv[jj] = *(const bf16x8*)&bpack[(((size_t)kt * 32 + (w * 4 + jj)) * 64 + l) * 8];
#pragma unroll
            for (int st = 0; st < 4; st++)
                av[st] = *(const bf16x8*)(abase + st * 16 * 136 + sub * 32);
#pragma unroll
            for (int st = 0; st < 4; st++)
#pragma unroll
                for (int jj = 0; jj < 4; jj++)
                    acc[st][jj] = __builtin_amdgcn_mfma_f32_16x16x32_bf16(av[st], bv[jj], acc[st][jj], 0, 0, 0);
        }
        __syncthreads();                        // done reading Ab[s&1]
    }

    // epilogue: val(s) = sum_h tanh(sc + bias_h) * state_h over this wave's 64 h
    float hb[4], hs[4];
#pragma unroll
    for (int jj = 0; jj < 4; jj++) {
        int h = (w * 4 + jj) * 16 + m;
        hb[jj] = Wc_b[h];
        hs[jj] = state[b * H_ + h];
    }
#pragma unroll
    for (int st = 0; st < 4; st++) {
#pragma unroll
        for (int rr = 0; rr < 4; rr++) {
            float val = 0.f;
#pragma unroll
            for (int jj = 0; jj < 4; jj++)
                val += tanh_fast(acc[st][jj][rr] + hb[jj]) * hs[jj];
            val += __shfl_xor(val, 1, 64);
            val += __shfl_xor(val, 2, 64);
            val += __shfl_xor(val, 4, 64);
            val += __shfl_xor(val, 8, 64);
            if (m == 0) partL[w][st * 16 + q * 4 + rr] = val;
        }
    }
    __syncthreads();
    if (t < 64) {
        float tot = 0.f;
#pragma unroll
        for (int ww = 0; ww < 8; ww++) tot += partL[ww][t];
        int s = s0 + t;
        int ei = enc_idx[b * S_ + s];
        scorec[b * S_ + s] = tanh_fast(tot) + (ei == 0 ? -1000.0f : 0.0f);
    }
}

// ---------------- exp pass + partial sums; c==16 handles score_c chunk ----------------
__global__ void k_exp(float* scoreg, float* scorec, float* partA, float* partC) {
    int blk = blockIdx.x;                       // 544 = 32 b * 17 chunks
    int b = blk / 17, c = blk % 17;
    int t = threadIdx.x;
    float sa = 0.f;
    if (c < 16) {
        int base = b * V_ + c * 2000;
        for (int i = t; i < 2000; i += 256) {
            float e = __expf(scoreg[base + i]);
            scoreg[base + i] = e;
            sa += e;
        }
    } else {
        int base = b * 1024;
        for (int i = t; i < 1024; i += 256) {
            float e = __expf(scorec[base + i]);
            scorec[base + i] = e;
            sa += e;
        }
    }
#pragma unroll
    for (int off = 32; off >= 1; off >>= 1) sa += __shfl_xor(sa, off, 64);
    __shared__ float rA[4];
    int w = t >> 6, l = t & 63;
    if (l == 0) rA[w] = sa;
    __syncthreads();
    if (t == 0) {
        float tot = rA[0] + rA[1] + rA[2] + rA[3];
        partA[blk] = tot;
        if (c == 16) partC[b] = tot;
    }
}

// ---------------- combine: row sums, global c-sum, match count/list ----------------
__global__ void k_combine(const float* partA, const float* partC, float* rowinv, float* invgc,
                          int* cnt, int* list, const int* enc_idx, const int* input_idx) {
    __shared__ float rs[32], rc[32];
    int t = threadIdx.x;
    if (t < 32) {
        float a = 0.f;
        for (int j = 0; j < 17; j++) a += partA[t * 17 + j];
        rs[t] = a; rc[t] = partC[t];
        rowinv[t] = 1.0f / a;
        cnt[t] = 0;
    }
    __syncthreads();
    if (t == 0) {
        float g = 0.f;
        for (int b = 0; b < 32; b++) g += rc[b] / rs[b];
        invgc[0] = 1.0f / g;
    }
    for (int i = t; i < B_ * S_; i += 512) {
        int b = i >> 10;
        if (enc_idx[i] == input_idx[b]) {
            int p = atomicAdd(&cnt[b], 1);
            list[b * S_ + p] = i & 1023;
        }
    }
}

// ---------------- normalize: prob_g -> out, prob_c -> ws, OOV fill ----------------
__global__ void k_write(const float* scoreg, const float* scorec, const float* rowinv,
                        float* out, float* probc) {
    int idx = blockIdx.x * 256 + threadIdx.x;
    if (idx < B_ * V_) {
        int b = idx / V_, v = idx - b * V_;
        out[b * VO_ + v] = scoreg[idx] * rowinv[b];
    } else if (idx < B_ * V_ + B_ * S_) {
        int j = idx - B_ * V_;
        int b = j >> 10;
        probc[j] = scorec[j] * rowinv[b];
    } else {
        int j = idx - B_ * V_ - B_ * S_;
        if (j < B_ * 12) {
            int b = j / 12;
            out[b * VO_ + V_ + (j - b * 12)] = 0.0001f;
        }
    }
}

// ---------------- scatter prob_c into out ----------------
__global__ void k_scatter(const float* probc, const int* enc_idx, float* out) {
    int idx = blockIdx.x * 256 + threadIdx.x;   // 32768 exact
    int b = idx >> 10;
    atomicAdd(&out[b * VO_ + enc_idx[idx]], probc[idx]);
}

// ---------------- weighted_out via sparse match list ----------------
__global__ void k_wo(const float* probc, const int* list, const int* cnt, const float* invgc,
                     const float* encoded, const float* bin, float* out2) {
    int b = blockIdx.x, t = threadIdx.x;
    __shared__ float aL[1024];
    __shared__ int   sL[1024];
    int n = cnt[b];
    float scale = invgc[0] * (n > 1 ? 1.0f / (float)n : 1.0f);
    for (int i = t; i < n; i += 256) {
        int s = list[b * S_ + i];
        sL[i] = s;
        aL[i] = probc[b * S_ + s] * scale;
    }
    __syncthreads();
    for (int d = t; d < D2_; d += 256) {
        float acc = 0.f;
        for (int i = 0; i < n; i++) {
            int s = sL[i];
            float ev = (d < 1024) ? encoded[((size_t)(b * S_ + s)) * 1024 + d] : bin[b * S_ + s];
            acc += aL[i] * ev;
        }
        out2[b * D2_ + d] = acc;
    }
}

extern "C" void kernel_launch(void* const* d_in, const int* in_sizes, int n_in,
                              void* d_out, int out_size, void* d_ws, size_t ws_size,
                              hipStream_t stream) {
    const int*   input_idx = (const int*)d_in[0];
    const float* encoded   = (const float*)d_in[1];
    const int*   enc_idx   = (const int*)d_in[2];
    const float* prev      = (const float*)d_in[3];
    const float* weighted  = (const float*)d_in[4];
    const float* bin       = (const float*)d_in[5];
    const int*   order     = (const int*)d_in[6];
    const float* embed     = (const float*)d_in[7];
    const float* W_ih      = (const float*)d_in[8];
    const float* b_ih      = (const float*)d_in[9];
    const float* W_hh      = (const float*)d_in[10];
    const float* b_hh      = (const float*)d_in[11];
    const float* Wo_w      = (const float*)d_in[12];
    const float* Wo_b      = (const float*)d_in[13];
    const float* Wc_w      = (const float*)d_in[14];
    const float* Wc_b      = (const float*)d_in[15];
    const float* Ws_w      = (const float*)d_in[16];
    const float* Ws_b      = (const float*)d_in[17];

    float* out  = (float*)d_out;
    float* out1 = out + B_ * VO_;             // state
    float* out2 = out1 + B_ * H_;             // weighted_out

    float* ws_f     = (float*)d_ws;
    float* w_state  = ws_f;                   // 16384
    float* w_prev   = ws_f + 16384;           // 16384
    float* w_x      = ws_f + 68736;           // 45056
    float* w_gi     = ws_f + 113792;          // 49152
    float* w_gh     = ws_f + 162944;          // 49152
    float* w_scoreg = ws_f + 212096;          // 1024000
    float* w_scorec = ws_f + 1236096;         // 32768
    float* w_probc  = ws_f + 1268864;         // 32768
    float* w_partA  = ws_f + 1301632;         // 544
    float* w_partC  = ws_f + 1302176;         // 32
    float* w_rowinv = ws_f + 1302208;         // 32
    float* w_invgc  = ws_f + 1302240;         // 1 (+7 pad)
    int*   w_cnt    = (int*)(ws_f + 1302248); // 32
    int*   w_list   = w_cnt + 32;             // 32768
    unsigned short* w_bpack = (unsigned short*)(ws_f + 1335048); // 589824 ushort, 16B-aligned

    k_prep<<<32, 256, 0, stream>>>(order, input_idx, embed, weighted, prev,
                                   encoded, bin, Ws_w, Ws_b, w_x, w_prev);
    k_pack_wc<<<2304, 256, 0, stream>>>(Wc_w, w_bpack);
    k_gi<<<768, 256, 16 * INP_ * sizeof(float), stream>>>(w_x, W_ih, b_ih, w_gi);
    k_gh<<<384, 256, B_ * H_ * sizeof(float), stream>>>(w_prev, W_hh, b_hh, w_gh);
    k_gate<<<64, 256, 0, stream>>>(w_gi, w_gh, w_prev, w_state, out1);
    k_scoreg<<<500, 256, 0, stream>>>(w_state, Wo_w, Wo_b, w_scoreg);
    k_sc<<<512, 512, 0, stream>>>(encoded, bin, w_bpack, Wc_b, w_state, enc_idx, w_scorec);
    k_exp<<<544, 256, 0, stream>>>(w_scoreg, w_scorec, w_partA, w_partC);
    k_combine<<<1, 512, 0, stream>>>(w_partA, w_partC, w_rowinv, w_invgc, w_cnt, w_list, enc_idx, input_idx);
    k_write<<<4130, 256, 0, stream>>>(w_scoreg, w_scorec, w_rowinv, out, w_probc);
    k_scatter<<<128, 256, 0, stream>>>(w_probc, enc_idx, out);
    k_wo<<<32, 256, 0, stream>>>(w_probc, w_list, w_cnt, w_invgc, encoded, bin, out2);
}